// Round 7
// baseline (503.891 us; speedup 1.0000x reference)
//
#include <hip/hip_runtime.h>

// Problem constants (fixed by reference)
#define CI    16
#define CO    16
#define HID   256
#define KPAD  288    // 256 + 32; k==256 row carries b2 (VALU-free bias), rest 0
#define NKK   9      // KPAD/32 MFMA K-steps (B side; W2b layout)
#define NKH   8      // kk frags held in LDS (kk=8 pad frag synthesized in regs)
#define NCH   144    // CI*9 columns per output channel
#define IMGH  128
#define IMGW  128
#define RSTR  132    // shPatch row stride in SHORTS (264 B, 8B-aligned)
#define RLEN  130    // valid window px per row: 128 + 2 halo
#define KKSTR (NCH * 32)        // shorts per kk block  = 4608
#define OSTRS (NKK * NCH * 32)  // shorts per o         = 41472

typedef float f32x4  __attribute__((ext_vector_type(4)));
typedef float f32x2  __attribute__((ext_vector_type(2)));
typedef short bf16x8 __attribute__((ext_vector_type(8)));

__device__ __host__ __forceinline__ short f2bf(float f) {
  union { float f; unsigned u; } c; c.f = f;
  unsigned b = c.u + 0x7FFFu + ((c.u >> 16) & 1u);   // RNE
  return (short)(b >> 16);
}

// ---------------------------------------------------------------------------
// Prep: W2 [256][2304] fp32 (+ b2[2304]) -> W2b [o][kk:9][n':144][k:32] bf16,
// K padded to 288 (row 256 = b2, rows 257..287 = 0).
// n-columns permuted dx-MAJOR: n' = dx*48 + i*3 + dyr -> dx is uniform per
// 16-wide n-tile, so the main kernel's patch contraction reads an aligned
// window with a per-pass constant shift. Contraction sums over n: order free.
// grid = 36 col-blocks * 9 kk = 324 blocks x 256 threads.
// ---------------------------------------------------------------------------
__global__ void prep_w2(const float* __restrict__ W2, const float* __restrict__ b2,
                        short* __restrict__ W2b) {
  __shared__ float tile[32][65];
  const int kk = blockIdx.x % NKK;
  const int colbase = (blockIdx.x / NKK) * 64;
  const int tid = threadIdx.x;

  for (int e = tid; e < 2048; e += 256) {
    int klr = e >> 6;          // 0..31
    int cc  = e & 63;
    int col = colbase + cc;
    float v;
    if (kk < 8) v = W2[(kk * 32 + klr) * (CO * NCH) + col];
    else        v = (klr == 0) ? b2[col] : 0.f;
    tile[klr][cc] = v;
  }
  __syncthreads();
  for (int e = tid; e < 2048; e += 256) {
    int cc = e >> 5;           // 0..63
    int kl = e & 31;
    int col = colbase + cc;
    int o = col / NCH;
    int n = col - o * NCH;
    int i = n / 9, q = n - i * 9;
    int dyr = q / 3, dx = q - dyr * 3;
    int np = dx * 48 + i * 3 + dyr;            // dx-major permutation
    W2b[(((o * NKK + kk) * NCH + np) << 5) + kl] = f2bf(tile[kl][cc]);
  }
}

// ---------------------------------------------------------------------------
// Main fused kernel, v18 = v14 wave roles (wave owns full M=128, channels
// {wv,+4,+8,+12} sequentially) + FULLY-UNROLLED K-loop with 4-buffer
// distance-3 B prefetch + v17's staged full-row flush.
// Post-mortem v14/v16/v17: MfmaUtil pinned ~35 in all three; A-read halving
// (v16/v17) LOST time -> the binder is per-kk-step LOAD LATENCY, not LDS or
// matrix-pipe throughput. v14's "#pragma unroll 1" t-loop serialized
// {B-loads(200cyc L2) -> A ds_reads(120cyc) -> MFMA} per step and blocked
// cross-step hoisting; distance-1 ping-pong gave only ~116cyc cover. All 8
// waves convoy in the same stall phase (round ~2150cyc vs 930cyc demand).
// v18: full unroll of the 9 kk-steps lets the scheduler software-pipeline
// loads across steps; bb[(t+3)&3] issued at step t, used at t+3 -> ~700cyc
// cover (3.5x L2 latency). Regs: acc 96 + B 48 + P2 32 + temps ~ 200 < 256.
// LDS 64+12.4 KB = 78.3 KB -> 2 blocks/CU; grid 512 = exactly 2/CU.
// grid = 4 batches * 128 rows = 512 blocks x 256 threads.
// ---------------------------------------------------------------------------
__global__ __launch_bounds__(256, 2)
void ngconv_main(const float* __restrict__ in, const float* __restrict__ foa,
                 const float* __restrict__ W1, const float* __restrict__ b1,
                 const short* __restrict__ W2b, float* __restrict__ out) {
  __shared__ __align__(16) short shHf[64 * 512];  // 64 frags = 64 KB; reused as out-staging
  __shared__ short shPatch[48 * RSTR];            // raw rows [i*3+dyr][xx] bf16, 12.4 KB

  const int tid  = threadIdx.x;
  const int lane = tid & 63;
  const int wv   = tid >> 6;        // 0..3: wave owns channels {wv, wv+4, wv+8, wv+12}
  const int c15  = lane & 15;
  const int quad = lane >> 4;

  const int blk = blockIdx.x;
  const int b   = blk >> 7;
  const int y   = blk & 127;

  const float fx  = foa[b * 2 + 0];
  const float fy  = foa[b * 2 + 1];
  const float dyv = (float)y - fy;

  const int ry0 = (y == 0) ? 1 : (y - 1);
  const int ry2 = (y == IMGH - 1) ? (IMGH - 2) : (y + 1);

  // ---- shPatch[r=i*3+dyr][xx]: reflect-extended row, xx in [0,130) maps to
  // image x = xx - 1. Patch value for (n'=(dx,i,dyr), px) = row[px+dx].
  for (int e = tid; e < 48 * RLEN; e += 256) {
    int r  = e / RLEN;                // 0..47 = i*3 + dyr
    int xx = e - r * RLEN;
    int i = r / 3, dyr = r - i * 3;
    int ryr = (dyr == 0) ? ry0 : ((dyr == 1) ? y : ry2);
    int x = xx - 1;
    x = (x < 0) ? 1 : ((x > IMGW - 1) ? (IMGW - 2) : x);   // reflect
    shPatch[r * RSTR + xx] = f2bf(in[((b * CI + i) * IMGH + ryr) * IMGW + x]);
  }

  // ---- shHf: H in fragment order, kk=0..7. frag(ms,kk) = A[16px][32k];
  // lane slot (c15=px, quad=k-octet). 128 px x 32 k-slots = 4096 = 16 exact its.
  for (int g = tid; g < 128 * 32; g += 256) {
    int px = g & 127;
    int ks = g >> 7;                  // 0..31 -> k0 = ks*8 < 256
    int k0 = ks << 3;
    float dxv = (float)px - fx;
    short hv[8];
    #pragma unroll
    for (int j = 0; j < 8; ++j) {
      int k = k0 + j;
      float h = fmaxf(fmaf(dxv, W1[k], fmaf(dyv, W1[HID + k], b1[k])), 0.f);
      hv[j] = f2bf(h);
    }
    int ms = px >> 4;                 // 0..7
    int kk = k0 >> 5;
    int lslot = ((k0 & 31) >> 3) * 16 + (px & 15);   // quad*16 + c15
    *(bf16x8*)&shHf[((ms * NKH + kk) << 9) + (lslot << 3)] = *(bf16x8*)hv;
  }

  // ---- kk=8 pad fragment, constant, in registers: k=256 -> 1.0 (b2 row)
  bf16x8 af8 = (bf16x8){0, 0, 0, 0, 0, 0, 0, 0};
  if (quad == 0) af8[0] = (short)0x3F80;   // bf16 1.0

  __syncthreads();

  // ---- main loop: 4 output channels per wave; results carried in regs
  float Pout[8];                           // [oj*2 + half]

  #pragma unroll 1
  for (int oj = 0; oj < 4; ++oj) {
    const int o = wv + oj * 4;
    const short* Bo = W2b + o * OSTRS + (c15 << 5) + (quad << 3);

    // per-oj partial sums (accumulate across all 3 passes; trees at the end)
    f32x2 P2[16];
    #pragma unroll
    for (int t = 0; t < 16; ++t) P2[t] = (f32x2){0.f, 0.f};

    #pragma unroll 1
    for (int pass = 0; pass < 3; ++pass) {
      const short* Bp = Bo + (pass * 3) * 512;   // first n-tile of this pass
      f32x4 acc[8][3];
      #pragma unroll
      for (int ms = 0; ms < 8; ++ms)
        #pragma unroll
        for (int j = 0; j < 3; ++j)
          acc[ms][j] = (f32x4){0.f, 0.f, 0.f, 0.f};

      // 4-buffer rotating B prefetch, distance 3, fully unrolled K-loop.
      bf16x8 bb[4][3];
      #pragma unroll
      for (int j = 0; j < 3; ++j) {
        bb[0][j] = *(const bf16x8*)&Bp[0 * KKSTR + (j << 9)];
        bb[1][j] = *(const bf16x8*)&Bp[1 * KKSTR + (j << 9)];
        bb[2][j] = *(const bf16x8*)&Bp[2 * KKSTR + (j << 9)];
      }

      #pragma unroll
      for (int t = 0; t < 9; ++t) {
        if (t + 3 <= 8) {                 // static under full unroll
          #pragma unroll
          for (int j = 0; j < 3; ++j)     // buffer (t+3)&3 freed at step t-1
            bb[(t + 3) & 3][j] = *(const bf16x8*)&Bp[(t + 3) * KKSTR + (j << 9)];
        }
        if (t < 8) {
          const short* hp = shHf + (t << 9) + (lane << 3);
          #pragma unroll
          for (int ms = 0; ms < 8; ++ms) {
            bf16x8 af = *(const bf16x8*)&hp[ms * (NKH << 9)];
            #pragma unroll
            for (int j = 0; j < 3; ++j)
              acc[ms][j] = __builtin_amdgcn_mfma_f32_16x16x32_bf16(
                  af, bb[t & 3][j], acc[ms][j], 0, 0, 0);
          }
        } else {                          // tail kk=8 (b2 K-row): af8 from regs
          #pragma unroll
          for (int ms = 0; ms < 8; ++ms)
            #pragma unroll
            for (int j = 0; j < 3; ++j)
              acc[ms][j] = __builtin_amdgcn_mfma_f32_16x16x32_bf16(
                  af8, bb[t & 3][j], acc[ms][j], 0, 0, 0);
        }
      }

      // ---- per-pass patch contraction into P2 (b2 already in acc).
      // n' = (pass*3+j)*16 + c15 is dx-major: dx == pass (wave-uniform),
      // row index = 16*j + c15, window = row[ms*16 + quad*4 + dx ..].
      // Aligned reads (b64 + b32) + two uniform 64-bit shifts.
      const int sh = pass << 4;          // 0 / 16 / 32 bits
      #pragma unroll
      for (int j = 0; j < 3; ++j) {
        const short* prow = &shPatch[((j << 4) + c15) * RSTR + (quad << 2)];
        #pragma unroll
        for (int ms = 0; ms < 8; ++ms) {
          uint2 u0 = *(const uint2*)&prow[ms * 16];           // ds_read_b64
          unsigned u1 = *(const unsigned*)&prow[ms * 16 + 4]; // ds_read_b32
          unsigned long long a0 =
              (unsigned long long)u0.x | ((unsigned long long)u0.y << 32);
          unsigned long long a1 =
              (unsigned long long)u0.y | ((unsigned long long)u1 << 32);
          unsigned d0 = (unsigned)(a0 >> sh);                // taps r=0,1
          unsigned d1 = (unsigned)(a1 >> sh);                // taps r=2,3
          float p0 = __uint_as_float(d0 << 16);
          float p1 = __uint_as_float(d0 & 0xFFFF0000u);
          float p2 = __uint_as_float(d1 << 16);
          float p3 = __uint_as_float(d1 & 0xFFFF0000u);
          f32x2 a01 = {acc[ms][j][0], acc[ms][j][1]};
          f32x2 a23 = {acc[ms][j][2], acc[ms][j][3]};
          P2[ms * 2 + 0] += a01 * (f32x2){p0, p1};           // v_pk_fma_f32
          P2[ms * 2 + 1] += a23 * (f32x2){p2, p3};
        }
      }
    }

    // ---- TWO reduce-scatter trees per oj -> registers (no barrier)
    #pragma unroll
    for (int half = 0; half < 2; ++half) {
      float P[16];
      #pragma unroll
      for (int t = 0; t < 16; ++t) P[t] = P2[half * 8 + (t >> 1)][t & 1];
      #pragma unroll
      for (int m = 8; m >= 1; m >>= 1) {
        const bool hi = (c15 & m) != 0;
        #pragma unroll
        for (int j = 0; j < m; ++j) {
          float keep = hi ? P[j + m] : P[j];
          float send = hi ? P[j] : P[j + m];
          float recv = __shfl_xor(send, m, 64);
          P[j] = keep + recv;
        }
      }
      Pout[oj * 2 + half] = P[0];
    }
  }

  // ---- single staged flush: reuse shHf (dead) as [16][128] f32 = 8 KB
  __syncthreads();                        // all K-loop LDS reads complete
  float* shO = (float*)shHf;
  const int pxpat = (c15 >> 2) * 16 + quad * 4 + (c15 & 3);
  #pragma unroll
  for (int oj = 0; oj < 4; ++oj)
    #pragma unroll
    for (int half = 0; half < 2; ++half)
      shO[(wv + oj * 4) * IMGW + half * 64 + pxpat] = Pout[oj * 2 + half];
  __syncthreads();
  #pragma unroll
  for (int u = 0; u < 2; ++u) {           // 512 float4s, 2 per thread
    int f   = u * 256 + tid;
    int row = f >> 5;                     // output channel 0..15
    int c4  = f & 31;
    float4 v = *(const float4*)&shO[row * IMGW + c4 * 4];
    *(float4*)&out[((b * CO + row) * IMGH + y) * IMGW + c4 * 4] = v;
  }
}

// ---------------------------------------------------------------------------
extern "C" void kernel_launch(void* const* d_in, const int* in_sizes, int n_in,
                              void* d_out, int out_size, void* d_ws, size_t ws_size,
                              hipStream_t stream) {
  const float* in  = (const float*)d_in[0];   // [4,16,128,128]
  const float* foa = (const float*)d_in[1];   // [4,2]
  const float* W1  = (const float*)d_in[2];   // [2,256]
  const float* b1  = (const float*)d_in[3];   // [256]
  const float* W2  = (const float*)d_in[4];   // [256,2304]
  const float* b2  = (const float*)d_in[5];   // [2304]
  float* out = (float*)d_out;
  short* W2b = (short*)d_ws;                  // 16*9*144*32 bf16 = 1.33 MB

  prep_w2<<<324, 256, 0, stream>>>(W2, b2, W2b);
  ngconv_main<<<512, 256, 0, stream>>>(in, foa, W1, b1, W2b, out);
}

// Round 8
// 215.648 us; speedup vs baseline: 2.3366x; 2.3366x over previous
//
#include <hip/hip_runtime.h>

// Problem constants
#define CI    16
#define CO    16
#define HID   256
#define IMGH  128
#define IMGW  128
#define RSTR  132            // shPatch row stride in shorts
#define RLEN  130            // 128 + 2 halo
#define W2PROW 2560          // shorts per k-row of W2p: 256 threads * 10 (9 cols + pad)
#define MAXEVT 512

typedef float f32x2 __attribute__((ext_vector_type(2)));

__device__ __host__ __forceinline__ short f2bf(float f) {
  union { float f; unsigned u; } c; c.f = f;
  unsigned b = c.u + 0x7FFFu + ((c.u >> 16) & 1u);   // RNE
  return (short)(b >> 16);
}
__device__ __forceinline__ float blo(unsigned u){ return __uint_as_float(u << 16); }
__device__ __forceinline__ float bhi(unsigned u){ return __uint_as_float(u & 0xFFFF0000u); }
__device__ __forceinline__ float bfu(short s){ return __uint_as_float(((unsigned)(unsigned short)s) << 16); }

// ---------------------------------------------------------------------------
// Prep: W2 [256][2304] fp32 -> W2p [k][t:256][10] bf16 where thread t's 9
// cols are 9t..9t+8 (col = o*144 + i*9 + q == 9*(o*16+i)+q), padded to 10
// shorts (20 B, 4-aligned) so each thread loads its slice as 5 dwords.
// ---------------------------------------------------------------------------
__global__ void prep_w2p(const float* __restrict__ W2, short* __restrict__ W2p) {
  const int k = blockIdx.x;          // 0..255
  const int t = threadIdx.x;         // 0..255
  const float* src = W2 + k * (CO * 144) + t * 9;
  short* dst = W2p + k * W2PROW + t * 10;
  #pragma unroll
  for (int q = 0; q < 9; ++q) dst[q] = f2bf(src[q]);
  dst[9] = 0;
}

// ---------------------------------------------------------------------------
// v19: BREAKPOINT-SWEEP algorithm (replaces the per-pixel MFMA GEMM).
// Key identity: per image row y, dy is constant, so h_k(x) = relu(a_k*dx+c_k)
// is piecewise-linear in x with ONE breakpoint th_k = fx - c_k/a_k. Hence
// kern(x,col) = S0(col) + dx*S1(col), where (S0,S1) change only at ~224
// breakpoint events per row: S0 += +-c_k*W2[k,:], S1 += +-a_k*W2[k,:].
// This replaces 1.18 MFLOP/px of GEMM with ~2 GFLOP total of VALU work
// (40x FLOP cut); L2 traffic per block (~1.15 MB of W2p rows) matches v14's.
// Thread t = (o = t>>4, ci = t&15) owns cols 9t..9t+8 (= all 9 taps of input
// channel ci for output channel o); S0/S1 held as f32x2 S[9] in registers.
// Sweep x = 0..127: apply bucket-x events (2-deep software-pipelined loads,
// NAMED registers only - v18's runtime-indexed arrays spilled to scratch),
// then contract 3x3 patch window (sliding regs) with S, reduce over the 16
// lanes of the o-group (shfl_xor 1/2/4/8), keeper lane stages to LDS.
// CONSISTENCY RULE: act-at-0 and the event are derived from the SAME theta
// comparison (independent h0>0 test can disagree near the boundary ->
// double-add of a full h_k, a large error).
// grid = 4 batches * 128 rows = 512 blocks x 256 threads; no MFMA at all.
// ---------------------------------------------------------------------------
__global__ __launch_bounds__(256, 2)
void ngconv_sweep(const float* __restrict__ in, const float* __restrict__ foa,
                  const float* __restrict__ W1, const float* __restrict__ b1,
                  const short* __restrict__ W2p, const float* __restrict__ b2,
                  float* __restrict__ out) {
  __shared__ short shPatch[48 * RSTR];     // reflect-extended rows, 12.4 KB
  __shared__ float shO[CO * 129];          // output staging (pad 129: no bank conflict)
  __shared__ unsigned evOff[MAXEVT];       // W2p byte offset per event
  __shared__ float evC[MAXEVT];            // signed c coef
  __shared__ float evA[MAXEVT];            // signed a coef
  __shared__ int bstart[IMGW + 1];         // bucket prefix
  __shared__ int cnt[IMGW];                // histogram / cursors
  __shared__ int nentSh;

  const int tid  = threadIdx.x;
  const int lane = tid & 63;
  const int o    = tid >> 4;        // output channel
  const int ic   = tid & 15;        // input channel

  const int blk = blockIdx.x;
  const int b = blk >> 7;
  const int y = blk & 127;

  const float fx = foa[b * 2 + 0];
  const float fy = foa[b * 2 + 1];
  const float dyv = (float)y - fy;
  const int ry0 = (y == 0) ? 1 : (y - 1);
  const int ry2 = (y == IMGH - 1) ? (IMGH - 2) : (y + 1);

  // ---- patch rows (identical to v14's verified setup)
  for (int e = tid; e < 48 * RLEN; e += 256) {
    int r = e / RLEN, xx = e - r * RLEN;
    int i2 = r / 3, dyr = r - i2 * 3;
    int ryr = (dyr == 0) ? ry0 : ((dyr == 1) ? y : ry2);
    int x = xx - 1;
    x = (x < 0) ? 1 : ((x > IMGW - 1) ? (IMGW - 2) : x);   // reflect
    shPatch[r * RSTR + xx] = f2bf(in[((b * CI + i2) * IMGH + ryr) * IMGW + x]);
  }

  for (int e = tid; e < IMGW; e += 256) cnt[e] = 0;
  __syncthreads();

  // ---- bucketing: thread tid handles k = tid
  float ka = W1[tid];                         // W1[0][k]
  float kc = fmaf(dyv, W1[HID + tid], b1[tid]);
  bool act0 = false;
  int xe = -1;
  if (ka != 0.f) {
    float th = fx - kc / ka;                  // breakpoint in x
    if (ka > 0.f) {                           // activates for x > th
      act0 = (th < 0.f);
      if (th >= 0.f && th < 127.f) xe = (int)floorf(th) + 1;
    } else {                                  // active for x < th
      act0 = (th > 0.f);
      if (th > 0.f && th < 127.f) xe = (int)floorf(th) + 1;
    }
  } else {
    act0 = (kc > 0.f);                        // constant h
  }
  if (act0)   atomicAdd(&cnt[0], 1);
  if (xe > 0) atomicAdd(&cnt[xe], 1);
  __syncthreads();
  if (tid == 0) {
    int s = 0;
    for (int x = 0; x < IMGW; ++x) { bstart[x] = s; s += cnt[x]; }
    bstart[IMGW] = s; nentSh = s;
  }
  __syncthreads();
  for (int e = tid; e < IMGW; e += 256) cnt[e] = bstart[e];   // cursors
  __syncthreads();
  if (act0) {
    int p = atomicAdd(&cnt[0], 1);
    evOff[p] = (unsigned)tid * (W2PROW * 2);
    evC[p] = kc; evA[p] = ka;
  }
  if (xe > 0) {
    int p = atomicAdd(&cnt[xe], 1);
    float sg = (ka > 0.f) ? 1.f : -1.f;       // activate vs deactivate
    evOff[p] = (unsigned)tid * (W2PROW * 2);
    evC[p] = sg * kc; evA[p] = sg * ka;
  }

  // ---- S init: S0 = b2 (net_out bias), S1 = 0. cols 9t..9t+8 contiguous.
  f32x2 S[9];
  {
    const float* bp = b2 + tid * 9;
    #pragma unroll
    for (int q = 0; q < 9; ++q) S[q] = (f32x2){bp[q], 0.f};
  }
  __syncthreads();
  const int nent = nentSh;

  // ---- event pipeline prime (2-deep, NAMED regs only)
  unsigned r0=0, r1=0, r2=0, r3=0, r4=0;      // row dwords for entry aptr
  float cC=0.f, cA=0.f;                       // coefs for entry aptr
  unsigned nOff=0; float nC=0.f, nA=0.f;      // meta for entry aptr+1
  if (nent > 0) {
    unsigned offs0 = evOff[0]; cC = evC[0]; cA = evA[0];
    const unsigned* gp = (const unsigned*)((const char*)W2p + offs0) + tid * 5;
    r0 = gp[0]; r1 = gp[1]; r2 = gp[2]; r3 = gp[3]; r4 = gp[4];
  }
  if (nent > 1) { nOff = evOff[1]; nC = evC[1]; nA = evA[1]; }

  // ---- sliding 3x3 patch window (this thread's channel ic), fp32 regs
  const short* pr0 = &shPatch[(ic * 3 + 0) * RSTR];
  const short* pr1 = &shPatch[(ic * 3 + 1) * RSTR];
  const short* pr2 = &shPatch[(ic * 3 + 2) * RSTR];
  float w00 = bfu(pr0[0]), w01 = bfu(pr0[1]);
  float w10 = bfu(pr1[0]), w11 = bfu(pr1[1]);
  float w20 = bfu(pr2[0]), w21 = bfu(pr2[1]);
  float f0 = bfu(pr0[2]), f1 = bfu(pr1[2]), f2 = bfu(pr2[2]);

  int aptr = 0;
  int endCur = bstart[1];

  #pragma unroll 1
  for (int x = 0; x < IMGW; ++x) {
    // prefetch next iteration's patch col + bucket end (hide LDS latency)
    float g0 = 0.f, g1 = 0.f, g2 = 0.f;
    if (x + 3 <= RLEN - 1) { g0 = bfu(pr0[x+3]); g1 = bfu(pr1[x+3]); g2 = bfu(pr2[x+3]); }
    int endNxt = (x + 2 <= IMGW) ? bstart[x + 2] : 0;

    // apply this bucket's events (block-uniform control flow)
    while (aptr < endCur) {
      unsigned tOff = 0; float tC = 0.f, tA = 0.f;
      if (aptr + 2 < nent) { tOff = evOff[aptr+2]; tC = evC[aptr+2]; tA = evA[aptr+2]; }
      unsigned m0=0, m1=0, m2=0, m3=0, m4=0;
      if (aptr + 1 < nent) {
        const unsigned* gp = (const unsigned*)((const char*)W2p + nOff) + tid * 5;
        m0 = gp[0]; m1 = gp[1]; m2 = gp[2]; m3 = gp[3]; m4 = gp[4];
      }
      f32x2 ca2 = (f32x2){cC, cA};
      float e0 = blo(r0), e1 = bhi(r0), e2 = blo(r1), e3 = bhi(r1), e4 = blo(r2);
      float e5 = bhi(r2), e6 = blo(r3), e7 = bhi(r3), e8 = blo(r4);
      S[0] += (f32x2){e0, e0} * ca2;          // v_pk_fma_f32
      S[1] += (f32x2){e1, e1} * ca2;
      S[2] += (f32x2){e2, e2} * ca2;
      S[3] += (f32x2){e3, e3} * ca2;
      S[4] += (f32x2){e4, e4} * ca2;
      S[5] += (f32x2){e5, e5} * ca2;
      S[6] += (f32x2){e6, e6} * ca2;
      S[7] += (f32x2){e7, e7} * ca2;
      S[8] += (f32x2){e8, e8} * ca2;
      r0 = m0; r1 = m1; r2 = m2; r3 = m3; r4 = m4; cC = nC; cA = nA;
      nOff = tOff; nC = tC; nA = tA;
      ++aptr;
    }

    // contraction: out(o,x) contribution = sum_q patch(ic,q,x) * S[q]
    float w02 = f0, w12 = f1, w22 = f2;
    f32x2 p = (f32x2){0.f, 0.f};
    p += (f32x2){w00, w00} * S[0];
    p += (f32x2){w01, w01} * S[1];
    p += (f32x2){w02, w02} * S[2];
    p += (f32x2){w10, w10} * S[3];
    p += (f32x2){w11, w11} * S[4];
    p += (f32x2){w12, w12} * S[5];
    p += (f32x2){w20, w20} * S[6];
    p += (f32x2){w21, w21} * S[7];
    p += (f32x2){w22, w22} * S[8];
    float px_ = p[0], py_ = p[1];
    #pragma unroll
    for (int m = 1; m <= 8; m <<= 1) {        // reduce over 16 lanes (same o)
      px_ += __shfl_xor(px_, m, 64);
      py_ += __shfl_xor(py_, m, 64);
    }
    if ((lane & 15) == (x & 15))
      shO[o * 129 + x] = fmaf((float)x - fx, py_, px_);

    w00 = w01; w01 = w02; w10 = w11; w11 = w12; w20 = w21; w21 = w22;
    f0 = g0; f1 = g1; f2 = g2;
    endCur = endNxt;
  }

  // ---- coalesced flush (full 512 B rows; v13/v15 split-write lesson)
  __syncthreads();
  #pragma unroll
  for (int u = 0; u < 2; ++u) {
    int f = u * 256 + tid;
    int row = f >> 5, c4 = f & 31;
    float4 v;
    v.x = shO[row * 129 + c4 * 4 + 0];
    v.y = shO[row * 129 + c4 * 4 + 1];
    v.z = shO[row * 129 + c4 * 4 + 2];
    v.w = shO[row * 129 + c4 * 4 + 3];
    *(float4*)&out[((b * CO + row) * IMGH + y) * IMGW + c4 * 4] = v;
  }
}

// ---------------------------------------------------------------------------
extern "C" void kernel_launch(void* const* d_in, const int* in_sizes, int n_in,
                              void* d_out, int out_size, void* d_ws, size_t ws_size,
                              hipStream_t stream) {
  const float* in  = (const float*)d_in[0];   // [4,16,128,128]
  const float* foa = (const float*)d_in[1];   // [4,2]
  const float* W1  = (const float*)d_in[2];   // [2,256]
  const float* b1  = (const float*)d_in[3];   // [256]
  const float* W2  = (const float*)d_in[4];   // [256,2304]
  const float* b2  = (const float*)d_in[5];   // [2304]
  float* out = (float*)d_out;
  short* W2p = (short*)d_ws;                  // 256*2560 bf16 = 1.31 MB

  prep_w2p<<<256, 256, 0, stream>>>(W2, W2p);
  ngconv_sweep<<<512, 256, 0, stream>>>(in, foa, W1, b1, W2p, b2, out);
}